// Round 1
// baseline (735.445 us; speedup 1.0000x reference)
//
#include <hip/hip_runtime.h>

// Problem: out[b,s,j] = sum_k x[b,s,k] * w_concat[inv_perm[j], k] + bias[j]
//   where w_concat rows 0..2047 = q8*s8, rows 2048..4095 = q4*s4.
// Strategy: pack permuted+dequant-ready weights Wp[j,k] = (bf16)q (exact, |q|<=128),
//   keep per-row scale_out[j] in f32, convert x->bf16 once, run ONE bf16 MFMA GEMM
//   with epilogue acc*scale+bias. No output permutation pass at all.

#define M_TOK 16384   // 8*2048 tokens
#define N_O   4096    // output channels
#define K_IN  4096    // input channels
#define N8F   2048    // int8-format channels

#define BM 128
#define BN 128
#define BK 32
#define NT (K_IN / BK)   // 128 K-steps

typedef __attribute__((ext_vector_type(8))) short bf16x8;
typedef __attribute__((ext_vector_type(4))) float f32x4;

__device__ __forceinline__ unsigned short f2bf(float f) {
  union { float f; unsigned u; } v; v.f = f;
  unsigned r = v.u + 0x7fffu + ((v.u >> 16) & 1u);   // RTNE
  return (unsigned short)(r >> 16);
}

__device__ __forceinline__ void gl_lds16(const void* g, void* l) {
  // async global->LDS, 16B/lane; LDS dest = wave-uniform base + lane*16
  __builtin_amdgcn_global_load_lds(
      (const __attribute__((address_space(1))) unsigned int*)g,
      (__attribute__((address_space(3))) unsigned int*)l, 16, 0, 0);
}

// ---------------- weight pack: Wp[j][k] = q_{inv[j]}[k] as bf16; scale_out[j] ----------
__global__ void pack_w_kernel(const int4* __restrict__ q8, const float* __restrict__ s8,
                              const int4* __restrict__ q4, const float* __restrict__ s4,
                              const int* __restrict__ inv_perm,
                              unsigned short* __restrict__ Wp, float* __restrict__ scale_out) {
  const int j = blockIdx.x;              // 4096 blocks
  const int c = inv_perm[j];
  const int4* src;
  float s;
  if (c < N8F) { src = q8 + (size_t)c * (K_IN / 4);         s = s8[c]; }
  else         { src = q4 + (size_t)(c - N8F) * (K_IN / 4); s = s4[c - N8F]; }
  if (threadIdx.x == 0) scale_out[j] = s;
  ushort4* dst = (ushort4*)(Wp + (size_t)j * K_IN);
  for (int k4 = threadIdx.x; k4 < K_IN / 4; k4 += blockDim.x) {
    int4 v = src[k4];
    ushort4 o;
    o.x = f2bf((float)v.x);  // integers |v|<=128 are exact in bf16
    o.y = f2bf((float)v.y);
    o.z = f2bf((float)v.z);
    o.w = f2bf((float)v.w);
    dst[k4] = o;
  }
}

// ---------------- x: f32 -> bf16 (RTNE), 8 elems/thread-iter ----------------
__global__ void cvt_x_kernel(const float4* __restrict__ x, uint4* __restrict__ xb, int n8) {
  int idx = blockIdx.x * blockDim.x + threadIdx.x;
  const int stride = gridDim.x * blockDim.x;
  for (; idx < n8; idx += stride) {
    float4 a = x[2 * idx], b = x[2 * idx + 1];
    uint4 o;
    o.x = f2bf(a.x) | ((unsigned)f2bf(a.y) << 16);
    o.y = f2bf(a.z) | ((unsigned)f2bf(a.w) << 16);
    o.z = f2bf(b.x) | ((unsigned)f2bf(b.y) << 16);
    o.w = f2bf(b.z) | ((unsigned)f2bf(b.w) << 16);
    xb[idx] = o;
  }
}

// ---------------- bf16 GEMM, 128x128 tile, BK=32, 4 waves (64x64 each) -------------
// XB=true : A staged from pre-converted bf16 via global_load_lds (fast path)
// XB=false: A staged from f32 via regs+convert (fallback if ws too small for xb)
template <bool XB>
__global__ __launch_bounds__(256, 2)
void gemm_kernel(const unsigned short* __restrict__ xb, const float* __restrict__ xf,
                 const unsigned short* __restrict__ Wp,
                 const float* __restrict__ scale, const float* __restrict__ bias,
                 float* __restrict__ out) {
  __shared__ __align__(16) unsigned short As[2][BM][BK];   // 2 x 8 KiB
  __shared__ __align__(16) unsigned short Bs[2][BN][BK];   // 2 x 8 KiB

  const int t = threadIdx.x;
  const int w = t >> 6, l = t & 63;
  const int bn = blockIdx.x & 31;        // N_O/BN = 32
  const int bm = blockIdx.x >> 5;
  const int row0 = bm * BM, col0 = bn * BN;

  // staging geometry (global_load_lds): issue i covers tile bytes [i*4096 + t*16)
  const int srow = t >> 2;               // tile row (64B rows)
  const int scol = (t & 3) * 8;          // elem offset within row
  const unsigned short* Bg = Wp + (size_t)(col0 + srow) * K_IN + scol;
  const unsigned short* Ag = nullptr;
  const float* Agf = nullptr;
  int farow = 0, fac0 = 0;
  if constexpr (XB) {
    Ag = xb + (size_t)(row0 + srow) * K_IN + scol;
  } else {
    farow = t >> 1;                      // 16 elems per thread
    fac0 = (t & 1) * 16;
    Agf = xf + (size_t)(row0 + farow) * K_IN + fac0;
  }

  auto stage = [&](int buf, int kt) {
    const unsigned short* bg = Bg + (size_t)kt * BK;
    char* bb = (char*)Bs + buf * 8192 + w * 1024;
    gl_lds16(bg, bb);
    gl_lds16(bg + (size_t)64 * K_IN, bb + 4096);
    if constexpr (XB) {
      const unsigned short* ag = Ag + (size_t)kt * BK;
      char* ab = (char*)As + buf * 8192 + w * 1024;
      gl_lds16(ag, ab);
      gl_lds16(ag + (size_t)64 * K_IN, ab + 4096);
    } else {
      const float* af = Agf + (size_t)kt * BK;
      unsigned int o[8];
#pragma unroll
      for (int i = 0; i < 4; ++i) {
        float4 v = *(const float4*)(af + i * 4);
        o[i * 2 + 0] = f2bf(v.x) | ((unsigned)f2bf(v.y) << 16);
        o[i * 2 + 1] = f2bf(v.z) | ((unsigned)f2bf(v.w) << 16);
      }
      uint4* d = (uint4*)((char*)As + buf * 8192 + farow * 64 + fac0 * 2);
      d[0] = make_uint4(o[0], o[1], o[2], o[3]);
      d[1] = make_uint4(o[4], o[5], o[6], o[7]);
    }
  };

  const int wr = w >> 1, wc = w & 1;     // 2x2 waves, 64x64 tile each
  const int lr = l & 15, lk = (l >> 4) * 8;

  f32x4 acc[4][4];
#pragma unroll
  for (int i = 0; i < 4; ++i)
#pragma unroll
    for (int j = 0; j < 4; ++j) acc[i][j] = (f32x4){0.f, 0.f, 0.f, 0.f};

  auto compute = [&](int buf) {
    bf16x8 av[4], bv[4];
#pragma unroll
    for (int fm = 0; fm < 4; ++fm)
      av[fm] = *(const bf16x8*)((const char*)As + buf * 8192 +
                                (wr * 64 + fm * 16 + lr) * 64 + lk * 2);
#pragma unroll
    for (int fn = 0; fn < 4; ++fn)
      bv[fn] = *(const bf16x8*)((const char*)Bs + buf * 8192 +
                                (wc * 64 + fn * 16 + lr) * 64 + lk * 2);
#pragma unroll
    for (int fm = 0; fm < 4; ++fm)
#pragma unroll
      for (int fn = 0; fn < 4; ++fn)
        acc[fm][fn] = __builtin_amdgcn_mfma_f32_16x16x32_bf16(av[fm], bv[fn],
                                                              acc[fm][fn], 0, 0, 0);
  };

  // 2-phase double-buffered loop: one barrier per K-step; staging of tile kt+1
  // overlaps compute of tile kt (vmcnt drained by the next __syncthreads).
  stage(0, 0);
  int cur = 0;
  for (int kt = 0; kt < NT; ++kt) {
    __syncthreads();
    if (kt + 1 < NT) stage(cur ^ 1, kt + 1);
    compute(cur);
    cur ^= 1;
  }

  // epilogue: C/D layout col=lane&15, row=(lane>>4)*4+reg ; out = acc*scale+bias
  const int orow = row0 + wr * 64 + (l >> 4) * 4;
  const int ocol0 = col0 + wc * 64 + lr;
#pragma unroll
  for (int fn = 0; fn < 4; ++fn) {
    const int col = ocol0 + fn * 16;
    const float sc = scale[col];
    const float bi = bias[col];
#pragma unroll
    for (int fm = 0; fm < 4; ++fm) {
      const int r = orow + fm * 16;
#pragma unroll
      for (int i = 0; i < 4; ++i)
        out[(size_t)(r + i) * N_O + col] = acc[fm][fn][i] * sc + bi;
    }
  }
}

extern "C" void kernel_launch(void* const* d_in, const int* in_sizes, int n_in,
                              void* d_out, int out_size, void* d_ws, size_t ws_size,
                              hipStream_t stream) {
  const float* x   = (const float*)d_in[0];
  const int*   q8  = (const int*)d_in[1];
  const float* s8  = (const float*)d_in[2];
  const int*   q4  = (const int*)d_in[3];
  const float* s4  = (const float*)d_in[4];
  const int*   inv = (const int*)d_in[5];
  const float* bias= (const float*)d_in[6];
  float* out = (float*)d_out;

  char* ws = (char*)d_ws;
  unsigned short* Wp = (unsigned short*)ws;                                // 32 MiB
  const size_t wp_bytes = (size_t)N_O * K_IN * 2;
  float* scale = (float*)(ws + wp_bytes);                                  // 16 KiB
  unsigned short* xb = (unsigned short*)(ws + wp_bytes + 65536);           // 128 MiB
  const size_t need_full = wp_bytes + 65536 + (size_t)M_TOK * K_IN * 2;

  pack_w_kernel<<<N_O, 256, 0, stream>>>((const int4*)q8, s8, (const int4*)q4, s4,
                                         inv, Wp, scale);

  const int grid = (M_TOK / BM) * (N_O / BN);   // 128 * 32 = 4096 blocks
  if (ws_size >= need_full) {
    cvt_x_kernel<<<2048, 256, 0, stream>>>((const float4*)x, (uint4*)xb,
                                           M_TOK * K_IN / 8);
    gemm_kernel<true><<<grid, 256, 0, stream>>>(xb, nullptr, Wp, scale, bias, out);
  } else {
    gemm_kernel<false><<<grid, 256, 0, stream>>>(nullptr, x, Wp, scale, bias, out);
  }
}

// Round 2
// 567.245 us; speedup vs baseline: 1.2965x; 1.2965x over previous
//
#include <hip/hip_runtime.h>

// out[b,s,j] = sum_k x[b,s,k] * w_concat[inv_perm[j], k] + bias[j]
// Folded: pack permuted bf16 weights Wp (exact: |q|<=128), per-row scale,
// x -> bf16 once, ONE bf16 MFMA GEMM with acc*scale+bias epilogue.
// GEMM: 256x256 tile, BK=64, 8 waves, 8-phase counted-vmcnt schedule (T3+T4),
// XOR-swizzled LDS (T2) via pre-swizzled global_load_lds source, setprio (T5).

#define M_TOK 16384
#define N_O   4096
#define K_IN  4096
#define N8F   2048
#define NT    (K_IN / 64)   // 64 K-tiles of BK=64

typedef __attribute__((ext_vector_type(8))) short bf16x8;
typedef __attribute__((ext_vector_type(4))) float f32x4;

__device__ __forceinline__ unsigned short f2bf(float f) {
  union { float f; unsigned u; } v; v.f = f;
  unsigned r = v.u + 0x7fffu + ((v.u >> 16) & 1u);   // RTNE
  return (unsigned short)(r >> 16);
}

__device__ __forceinline__ void gl_lds16(const void* g, void* l) {
  __builtin_amdgcn_global_load_lds(
      (const __attribute__((address_space(1))) unsigned int*)g,
      (__attribute__((address_space(3))) unsigned int*)l, 16, 0, 0);
}

// ---------------- weight pack: Wp[j][k] = q_{inv[j]}[k] as bf16; scale_out[j] -------
__global__ void pack_w_kernel(const int4* __restrict__ q8, const float* __restrict__ s8,
                              const int4* __restrict__ q4, const float* __restrict__ s4,
                              const int* __restrict__ inv_perm,
                              unsigned short* __restrict__ Wp, float* __restrict__ scale_out) {
  const int j = blockIdx.x;
  const int c = inv_perm[j];
  const int4* src;
  float s;
  if (c < N8F) { src = q8 + (size_t)c * (K_IN / 4);         s = s8[c]; }
  else         { src = q4 + (size_t)(c - N8F) * (K_IN / 4); s = s4[c - N8F]; }
  if (threadIdx.x == 0) scale_out[j] = s;
  ushort4* dst = (ushort4*)(Wp + (size_t)j * K_IN);
  for (int k4 = threadIdx.x; k4 < K_IN / 4; k4 += blockDim.x) {
    int4 v = src[k4];
    ushort4 o;
    o.x = f2bf((float)v.x);
    o.y = f2bf((float)v.y);
    o.z = f2bf((float)v.z);
    o.w = f2bf((float)v.w);
    dst[k4] = o;
  }
}

// ---------------- x: f32 -> bf16 (RTNE) ----------------
__global__ void cvt_x_kernel(const float4* __restrict__ x, uint4* __restrict__ xb, int n8) {
  int idx = blockIdx.x * blockDim.x + threadIdx.x;
  const int stride = gridDim.x * blockDim.x;
  for (; idx < n8; idx += stride) {
    float4 a = x[2 * idx], b = x[2 * idx + 1];
    uint4 o;
    o.x = f2bf(a.x) | ((unsigned)f2bf(a.y) << 16);
    o.y = f2bf(a.z) | ((unsigned)f2bf(a.w) << 16);
    o.z = f2bf(b.x) | ((unsigned)f2bf(b.y) << 16);
    o.w = f2bf(b.z) | ((unsigned)f2bf(b.w) << 16);
    xb[idx] = o;
  }
}

// ================= 256x256 8-phase GEMM =================
// LDS map (bytes): buf*65536 + { A: half*16384 | B: 32768 + half*16384 }
// half = 128 rows x 64 bf16 (128B rows), swizzle: phys_colbyte = log ^ ((row&7)<<4)
__global__ __launch_bounds__(512, 2)
void gemm8p(const unsigned short* __restrict__ xb, const unsigned short* __restrict__ Wp,
            const float* __restrict__ scale, const float* __restrict__ bias,
            float* __restrict__ out) {
  __shared__ __align__(16) char sm[131072];
  const int t = threadIdx.x;
  const int w = t >> 6, l = t & 63;
  const int wr = w >> 2, wc = w & 3;          // 2M x 4N waves
  const int bm = blockIdx.x >> 4, bn = blockIdx.x & 15;
  const int row0 = bm * 256, col0 = bn * 256;

  // --- staging: per-lane pre-swizzled global source (rule #21) ---
  const int srow = l >> 3;                              // row within 8-row group
  const int schunk = ((l & 7) ^ srow) * 16;             // inverse-swizzled 16B chunk
  const char* aG = (const char*)xb + (size_t)(row0 + w * 16 + srow) * (K_IN * 2) + schunk;
  const char* bG = (const char*)Wp + (size_t)(col0 + w * 16 + srow) * (K_IN * 2) + schunk;
  char* aL0 = sm + w * 2048;                            // + buf*65536 + h*16384
  char* bL0 = sm + 32768 + w * 2048;

  auto stageA = [&](int buf, int kt, int h) {
    const char* g = aG + (size_t)h * (128 * K_IN * 2) + (size_t)kt * 128;
    char* p = aL0 + buf * 65536 + h * 16384;
    gl_lds16(g, p);
    gl_lds16(g + 8 * (K_IN * 2), p + 1024);
  };
  auto stageB = [&](int buf, int kt, int h) {
    const char* g = bG + (size_t)h * (128 * K_IN * 2) + (size_t)kt * 128;
    char* p = bL0 + buf * 65536 + h * 16384;
    gl_lds16(g, p);
    gl_lds16(g + 8 * (K_IN * 2), p + 1024);
  };

  // --- fragment-read per-lane offsets (swizzled) ---
  const int lrow128 = (l & 15) * 128;
  const int cb0 = (((l >> 4) << 4) ^ ((l & 7) << 4));   // kk=0 colbyte; kk=1: ^64
  const int aWoff = wr * 16384 + lrow128;
  const int bWoff = 32768 + (wc >> 1) * 16384 + (wc & 1) * 8192 + lrow128;

  f32x4 acc[8][4];
#pragma unroll
  for (int m = 0; m < 8; ++m)
#pragma unroll
    for (int n = 0; n < 4; ++n) acc[m][n] = (f32x4){0.f, 0.f, 0.f, 0.f};

  // --- prologue: tile0 fully + tile1 {B0,B1,A0}; wait tile0 (vmcnt 14->6) ---
  stageB(0, 0, 0); stageB(0, 0, 1); stageA(0, 0, 0); stageA(0, 0, 1);
  stageB(1, 1, 0); stageB(1, 1, 1); stageA(1, 1, 0);
  asm volatile("s_waitcnt vmcnt(6)" ::: "memory");
  __builtin_amdgcn_s_barrier();

  bf16x8 bfr[4][2], afr[2][2], afr2[2][2];

  for (int kt = 0; kt < NT; ++kt) {
    const int cur = kt & 1;
    const char* smA = sm + cur * 65536 + aWoff;
    const char* smB = sm + cur * 65536 + bWoff;

    // ---- phase 1: ds_read all B (8) + A mg0 (4); stage A1(kt+1) -> buf^1
#pragma unroll
    for (int n = 0; n < 4; ++n) {
      bfr[n][0] = *(const bf16x8*)(smB + n * 2048 + cb0);
      bfr[n][1] = *(const bf16x8*)(smB + n * 2048 + (cb0 ^ 64));
    }
#pragma unroll
    for (int m = 0; m < 2; ++m) {
      afr[m][0] = *(const bf16x8*)(smA + m * 2048 + cb0);
      afr[m][1] = *(const bf16x8*)(smA + m * 2048 + (cb0 ^ 64));
    }
    if (kt + 1 < NT) stageA(cur ^ 1, kt + 1, 1);
    __builtin_amdgcn_s_barrier();
    asm volatile("s_waitcnt lgkmcnt(0)" ::: "memory");
    __builtin_amdgcn_s_setprio(1);
#pragma unroll
    for (int m = 0; m < 2; ++m)
#pragma unroll
      for (int n = 0; n < 4; ++n)
#pragma unroll
        for (int kk = 0; kk < 2; ++kk)
          acc[m][n] = __builtin_amdgcn_mfma_f32_16x16x32_bf16(afr[m][kk], bfr[n][kk],
                                                              acc[m][n], 0, 0, 0);
    __builtin_amdgcn_s_setprio(0);
    __builtin_amdgcn_s_barrier();

    // ---- phase 2: ds_read A mg1 (4); stage B0(kt+2) -> buf cur (region free since p1)
#pragma unroll
    for (int m = 0; m < 2; ++m) {
      afr[m][0] = *(const bf16x8*)(smA + (2 + m) * 2048 + cb0);
      afr[m][1] = *(const bf16x8*)(smA + (2 + m) * 2048 + (cb0 ^ 64));
    }
    if (kt + 2 < NT) stageB(cur, kt + 2, 0);
    __builtin_amdgcn_s_barrier();
    asm volatile("s_waitcnt lgkmcnt(0)" ::: "memory");
    __builtin_amdgcn_s_setprio(1);
#pragma unroll
    for (int m = 0; m < 2; ++m)
#pragma unroll
      for (int n = 0; n < 4; ++n)
#pragma unroll
        for (int kk = 0; kk < 2; ++kk)
          acc[2 + m][n] = __builtin_amdgcn_mfma_f32_16x16x32_bf16(afr[m][kk], bfr[n][kk],
                                                                  acc[2 + m][n], 0, 0, 0);
    __builtin_amdgcn_s_setprio(0);
    __builtin_amdgcn_s_barrier();

    // ---- phase 3: ds_read A mg2 (4) + A mg3 prefetch (4); stage B1(kt+2)
#pragma unroll
    for (int m = 0; m < 2; ++m) {
      afr[m][0]  = *(const bf16x8*)(smA + (4 + m) * 2048 + cb0);
      afr[m][1]  = *(const bf16x8*)(smA + (4 + m) * 2048 + (cb0 ^ 64));
      afr2[m][0] = *(const bf16x8*)(smA + (6 + m) * 2048 + cb0);
      afr2[m][1] = *(const bf16x8*)(smA + (6 + m) * 2048 + (cb0 ^ 64));
    }
    if (kt + 2 < NT) stageB(cur, kt + 2, 1);
    __builtin_amdgcn_s_barrier();
    asm volatile("s_waitcnt lgkmcnt(0)" ::: "memory");   // frees A regions of buf cur
    __builtin_amdgcn_s_setprio(1);
#pragma unroll
    for (int m = 0; m < 2; ++m)
#pragma unroll
      for (int n = 0; n < 4; ++n)
#pragma unroll
        for (int kk = 0; kk < 2; ++kk)
          acc[4 + m][n] = __builtin_amdgcn_mfma_f32_16x16x32_bf16(afr[m][kk], bfr[n][kk],
                                                                  acc[4 + m][n], 0, 0, 0);
    __builtin_amdgcn_s_setprio(0);
    __builtin_amdgcn_s_barrier();

    // ---- phase 4: stage A0(kt+2); counted vmcnt (tile kt+1 landed, 3 halves in flight)
    if (kt + 2 < NT) {
      stageA(cur, kt + 2, 0);
      asm volatile("s_waitcnt vmcnt(6)" ::: "memory");
    } else {
      asm volatile("s_waitcnt vmcnt(0)" ::: "memory");
    }
    __builtin_amdgcn_s_barrier();
    __builtin_amdgcn_s_setprio(1);
#pragma unroll
    for (int m = 0; m < 2; ++m)
#pragma unroll
      for (int n = 0; n < 4; ++n)
#pragma unroll
        for (int kk = 0; kk < 2; ++kk)
          acc[6 + m][n] = __builtin_amdgcn_mfma_f32_16x16x32_bf16(afr2[m][kk], bfr[n][kk],
                                                                  acc[6 + m][n], 0, 0, 0);
    __builtin_amdgcn_s_setprio(0);
    __builtin_amdgcn_s_barrier();
  }

  // ---- epilogue: C/D layout col=lane&15, row=(lane>>4)*4+i ; out = acc*scale+bias
  const int orow0 = row0 + wr * 128 + ((l >> 4) << 2);
  const int ocol0 = col0 + wc * 64 + (l & 15);
#pragma unroll
  for (int n = 0; n < 4; ++n) {
    const int col = ocol0 + n * 16;
    const float sc = scale[col];
    const float bi = bias[col];
#pragma unroll
    for (int m = 0; m < 8; ++m) {
      const int r = orow0 + m * 16;
#pragma unroll
      for (int i = 0; i < 4; ++i)
        out[(size_t)(r + i) * N_O + col] = acc[m][n][i] * sc + bi;
    }
  }
}

// ================= fallback (ws too small for xb): round-0 128^2, f32 A staging ======
__global__ __launch_bounds__(256, 2)
void gemm_fb(const float* __restrict__ xf, const unsigned short* __restrict__ Wp,
             const float* __restrict__ scale, const float* __restrict__ bias,
             float* __restrict__ out) {
  __shared__ __align__(16) unsigned short As[2][128][32];
  __shared__ __align__(16) unsigned short Bs[2][128][32];
  const int t = threadIdx.x;
  const int w = t >> 6, l = t & 63;
  const int bn = blockIdx.x & 31;
  const int bm = blockIdx.x >> 5;
  const int row0 = bm * 128, col0 = bn * 128;
  const int srow = t >> 2, scol = (t & 3) * 8;
  const unsigned short* Bg = Wp + (size_t)(col0 + srow) * K_IN + scol;
  const int farow = t >> 1, fac0 = (t & 1) * 16;
  const float* Agf = xf + (size_t)(row0 + farow) * K_IN + fac0;

  auto stage = [&](int buf, int kt) {
    const unsigned short* bg = Bg + (size_t)kt * 32;
    char* bb = (char*)Bs + buf * 8192 + w * 1024;
    gl_lds16(bg, bb);
    gl_lds16(bg + (size_t)64 * K_IN, bb + 4096);
    const float* af = Agf + (size_t)kt * 32;
    unsigned int o[8];
#pragma unroll
    for (int i = 0; i < 4; ++i) {
      float4 v = *(const float4*)(af + i * 4);
      o[i * 2 + 0] = f2bf(v.x) | ((unsigned)f2bf(v.y) << 16);
      o[i * 2 + 1] = f2bf(v.z) | ((unsigned)f2bf(v.w) << 16);
    }
    uint4* d = (uint4*)((char*)As + buf * 8192 + farow * 64 + fac0 * 2);
    d[0] = make_uint4(o[0], o[1], o[2], o[3]);
    d[1] = make_uint4(o[4], o[5], o[6], o[7]);
  };

  const int wr = w >> 1, wc = w & 1;
  const int lr = l & 15, lk = (l >> 4) * 8;
  f32x4 acc[4][4];
#pragma unroll
  for (int i = 0; i < 4; ++i)
#pragma unroll
    for (int j = 0; j < 4; ++j) acc[i][j] = (f32x4){0.f, 0.f, 0.f, 0.f};

  stage(0, 0);
  int cur = 0;
  for (int kt = 0; kt < K_IN / 32; ++kt) {
    __syncthreads();
    if (kt + 1 < K_IN / 32) stage(cur ^ 1, kt + 1);
    bf16x8 av[4], bv[4];
#pragma unroll
    for (int fm = 0; fm < 4; ++fm)
      av[fm] = *(const bf16x8*)((const char*)As + cur * 8192 + (wr * 64 + fm * 16 + lr) * 64 + lk * 2);
#pragma unroll
    for (int fn = 0; fn < 4; ++fn)
      bv[fn] = *(const bf16x8*)((const char*)Bs + cur * 8192 + (wc * 64 + fn * 16 + lr) * 64 + lk * 2);
#pragma unroll
    for (int fm = 0; fm < 4; ++fm)
#pragma unroll
      for (int fn = 0; fn < 4; ++fn)
        acc[fm][fn] = __builtin_amdgcn_mfma_f32_16x16x32_bf16(av[fm], bv[fn], acc[fm][fn], 0, 0, 0);
    cur ^= 1;
  }
  const int orow = row0 + wr * 64 + (l >> 4) * 4;
  const int ocol0 = col0 + wc * 64 + lr;
#pragma unroll
  for (int fn = 0; fn < 4; ++fn) {
    const int col = ocol0 + fn * 16;
    const float sc = scale[col];
    const float bi = bias[col];
#pragma unroll
    for (int fm = 0; fm < 4; ++fm) {
      const int r = orow + fm * 16;
#pragma unroll
      for (int i = 0; i < 4; ++i)
        out[(size_t)(r + i) * N_O + col] = acc[fm][fn][i] * sc + bi;
    }
  }
}

extern "C" void kernel_launch(void* const* d_in, const int* in_sizes, int n_in,
                              void* d_out, int out_size, void* d_ws, size_t ws_size,
                              hipStream_t stream) {
  const float* x    = (const float*)d_in[0];
  const int*   q8   = (const int*)d_in[1];
  const float* s8   = (const float*)d_in[2];
  const int*   q4   = (const int*)d_in[3];
  const float* s4   = (const float*)d_in[4];
  const int*   inv  = (const int*)d_in[5];
  const float* bias = (const float*)d_in[6];
  float* out = (float*)d_out;

  char* ws = (char*)d_ws;
  unsigned short* Wp = (unsigned short*)ws;                         // 32 MiB
  const size_t wp_bytes = (size_t)N_O * K_IN * 2;
  float* scale = (float*)(ws + wp_bytes);                           // 16 KiB
  unsigned short* xb = (unsigned short*)(ws + wp_bytes + 65536);    // 128 MiB
  const size_t need_full = wp_bytes + 65536 + (size_t)M_TOK * K_IN * 2;

  pack_w_kernel<<<N_O, 256, 0, stream>>>((const int4*)q8, s8, (const int4*)q4, s4,
                                         inv, Wp, scale);

  if (ws_size >= need_full) {
    cvt_x_kernel<<<2048, 256, 0, stream>>>((const float4*)x, (uint4*)xb,
                                           M_TOK * K_IN / 8);
    gemm8p<<<(M_TOK / 256) * (N_O / 256), 512, 0, stream>>>(xb, Wp, scale, bias, out);
  } else {
    gemm_fb<<<(M_TOK / 128) * (N_O / 128), 256, 0, stream>>>(x, Wp, scale, bias, out);
  }
}